// Round 2
// baseline (496.697 us; speedup 1.0000x reference)
//
#include <hip/hip_runtime.h>
#include <math.h>

// Problem constants
#define BB 8
#define TT 8192
#define FF 1024
#define HH 256
#define OO 2
#define MT 64               // rows per block
#define NBLK ((BB*TT)/MT)   // 1024 main blocks
#define PBAG (TT/MT)        // 128 blocks per bag
#define PSTR 260            // floats per partial record: [m, l, acc[256], pad2]

typedef __attribute__((ext_vector_type(8))) short bf16x8;
typedef __attribute__((ext_vector_type(4))) float f32x4;

__device__ __forceinline__ float b2f(unsigned short s) {
    union { unsigned u; float f; } v; v.u = ((unsigned)s) << 16; return v.f;
}
__device__ __forceinline__ unsigned short f2b(float f) {
    union { float f; unsigned u; } v; v.f = f;
    unsigned u = v.u;
    return (unsigned short)((u + 0x7fffu + ((u >> 16) & 1u)) >> 16);
}

// ---------------- prep: LDS-tiled transpose + bf16 convert ----------------
// W1 (1024x256) -> W1t (256x1024); Wv,Wu (256x256) -> Wvt,Wut (256x256)
// 64x64 tiles, coalesced reads AND writes (the round-0 version did scattered
// 2-byte cross-XCD writes and ate ~280us).
__global__ __launch_bounds__(256)
void mil_prep(const float* __restrict__ W1,
              const float* __restrict__ Wv,
              const float* __restrict__ Wu,
              unsigned short* __restrict__ W1t,
              unsigned short* __restrict__ Wvt,
              unsigned short* __restrict__ Wut) {
    __shared__ unsigned short T[64 * 72];   // transposed tile, stride 72 (16B-aligned rows)
    const int b = blockIdx.x;
    const int t = threadIdx.x;
    const float* src;
    unsigned short* dst;
    int kt, nt, dstld;
    if (b < 64)      { src = W1; dst = W1t; kt = b >> 2;        nt = b & 3;        dstld = 1024; }
    else if (b < 80) { src = Wv; dst = Wvt; kt = (b - 64) >> 2; nt = (b - 64) & 3; dstld = 256; }
    else             { src = Wu; dst = Wut; kt = (b - 80) >> 2; nt = (b - 80) & 3; dstld = 256; }

    // read 64x64 fp32 tile at (kt*64, nt*64), store transposed bf16 into LDS
#pragma unroll
    for (int i = 0; i < 4; ++i) {
        int f = t + i * 256;
        int r = f >> 4, c = (f & 15) * 4;
        float4 v = *(const float4*)(src + (size_t)(kt * 64 + r) * 256 + nt * 64 + c);
        T[(c + 0) * 72 + r] = f2b(v.x);
        T[(c + 1) * 72 + r] = f2b(v.y);
        T[(c + 2) * 72 + r] = f2b(v.z);
        T[(c + 3) * 72 + r] = f2b(v.w);
    }
    __syncthreads();
    // write 64 rows x 64 cols bf16, coalesced 16B chunks
#pragma unroll
    for (int i = 0; i < 2; ++i) {
        int f = t + i * 256;
        int r = f >> 3, s = (f & 7) * 8;
        *(uint4*)(dst + (size_t)(nt * 64 + r) * dstld + kt * 64 + s) = *(uint4*)&T[r * 72 + s];
    }
}

// ---------------- main fused kernel ----------------
// Per block: 64 rows of one bag.
// Stage1: h = relu(bags@W1+b1). A staged via LDS (shared by 4 waves, fp32->bf16
//   once), B-frags loaded DIRECTLY global->VGPR (W1t is L2-resident; each wave
//   only ever touches its own 64 N-rows, so LDS staging of B had zero reuse).
//   bags tile kb+1 register-prefetched during MFMA on kb.
// Stage2: Gv=tanh(h@Wv+bv), Gu=sigmoid(h@Wu+bu) fused in one K-loop, direct
//   global B-frags, no barriers; N split in 2 chunks to cap VGPRs.
// Stage3: block-local online softmax partials (m, l, sum w*h) -> workspace.
__global__ __launch_bounds__(256, 3)
void mil_main(const float* __restrict__ bags,
              const unsigned char* __restrict__ mask,
              const float* __restrict__ b1,
              const float* __restrict__ bv,
              const float* __restrict__ bu,
              const float* __restrict__ ww,
              const float* __restrict__ bwp,
              const unsigned short* __restrict__ W1t,
              const unsigned short* __restrict__ Wvt,
              const unsigned short* __restrict__ Wut,
              float* __restrict__ P) {
    const int tid  = threadIdx.x;
    const int wave = tid >> 6;
    const int lane = tid & 63;
    const int l15  = lane & 15;
    const int quad = lane >> 4;
    const int blk  = blockIdx.x;
    const int row0 = blk * MT;            // global row in (B*T)
    const int bag  = blk >> 7;            // 128 blocks per bag
    const int trow = (blk & 127) * MT;    // row within bag

    // LDS: 9216 + 33792 = 43008 B -> 3 blocks/CU
    __shared__ unsigned short As[MT * 72];     // stride 72: 16B-aligned, 2-way alias (free)
    __shared__ unsigned short Hs[MT * 264];    // stride 264: 16B-aligned, 2-way alias

    const float bwv = bwp[0];

    // ---------------- stage 1: h = relu(bags @ W1 + b1) ----------------
    f32x4 acc[4][4];
#pragma unroll
    for (int mi = 0; mi < 4; ++mi)
#pragma unroll
        for (int ni = 0; ni < 4; ++ni)
            acc[mi][ni] = (f32x4){0.f, 0.f, 0.f, 0.f};

    const float* bagrow = bags + (size_t)row0 * FF;

    // register-prefetch the first bags tile
    float4 pf[4];
    int pr[4], pc[4];
#pragma unroll
    for (int i = 0; i < 4; ++i) {
        int f = tid + i * 256;
        pr[i] = f >> 4;
        pc[i] = (f & 15) * 4;
        pf[i] = *(const float4*)(bagrow + (size_t)pr[i] * FF + pc[i]);
    }

    for (int kb = 0; kb < FF / 64; ++kb) {
        __syncthreads();   // prev iter's As reads done
#pragma unroll
        for (int i = 0; i < 4; ++i) {
            unsigned p0 = (unsigned)f2b(pf[i].x) | ((unsigned)f2b(pf[i].y) << 16);
            unsigned p1 = (unsigned)f2b(pf[i].z) | ((unsigned)f2b(pf[i].w) << 16);
            *(uint2*)&As[pr[i] * 72 + pc[i]] = make_uint2(p0, p1);
        }
        __syncthreads();
        // B-frags for this tile (oldest vmem ops -> their waits won't drain pf)
        bf16x8 bfr[2][4];
#pragma unroll
        for (int k0i = 0; k0i < 2; ++k0i)
#pragma unroll
            for (int ni = 0; ni < 4; ++ni)
                bfr[k0i][ni] = *(const bf16x8*)(W1t + (size_t)(wave * 64 + ni * 16 + l15) * 1024
                                                + kb * 64 + k0i * 32 + quad * 8);
        // prefetch next bags tile (younger; stays in flight through the MFMAs)
        if (kb < FF / 64 - 1) {
#pragma unroll
            for (int i = 0; i < 4; ++i)
                pf[i] = *(const float4*)(bagrow + (size_t)pr[i] * FF + (kb + 1) * 64 + pc[i]);
        }
#pragma unroll
        for (int k0i = 0; k0i < 2; ++k0i) {
            bf16x8 afr[4];
#pragma unroll
            for (int mi = 0; mi < 4; ++mi)
                afr[mi] = *(const bf16x8*)&As[(mi * 16 + l15) * 72 + k0i * 32 + quad * 8];
#pragma unroll
            for (int mi = 0; mi < 4; ++mi)
#pragma unroll
                for (int ni = 0; ni < 4; ++ni)
                    acc[mi][ni] = __builtin_amdgcn_mfma_f32_16x16x32_bf16(afr[mi], bfr[k0i][ni], acc[mi][ni], 0, 0, 0);
        }
    }

    // Epilogue: +b1, relu, write Hs (bf16). D layout: col=lane&15, row=quad*4+reg.
    {
        float bb[4];
#pragma unroll
        for (int ni = 0; ni < 4; ++ni) bb[ni] = b1[wave * 64 + ni * 16 + l15];
#pragma unroll
        for (int mi = 0; mi < 4; ++mi)
#pragma unroll
            for (int ni = 0; ni < 4; ++ni) {
                int n = wave * 64 + ni * 16 + l15;
#pragma unroll
                for (int r = 0; r < 4; ++r) {
                    int m = mi * 16 + quad * 4 + r;
                    float h = acc[mi][ni][r] + bb[ni];
                    h = fmaxf(h, 0.f);
                    Hs[m * 264 + n] = f2b(h);
                }
            }
    }
    __syncthreads();   // all As reads done; Hs visible to everyone

    // Scratch carved out of the (dead) As region
    float* logits = (float*)As;        // 64 floats
    float* wrow   = logits + 64;       // 64 floats
    float* sc     = wrow + 64;         // 2 floats
    if (tid < MT) logits[tid] = 0.f;
    __syncthreads();   // logits=0 visible before any atomicAdd

    // ---------------- stage 2: gated attention (fused tanh/sigmoid passes) ----------------
    float rsum[4][4];
#pragma unroll
    for (int mi = 0; mi < 4; ++mi)
#pragma unroll
        for (int r = 0; r < 4; ++r) rsum[mi][r] = 0.f;

#pragma unroll
    for (int nc = 0; nc < 2; ++nc) {
        f32x4 av[4][2], au[4][2];
#pragma unroll
        for (int mi = 0; mi < 4; ++mi)
#pragma unroll
            for (int j = 0; j < 2; ++j) {
                av[mi][j] = (f32x4){0.f, 0.f, 0.f, 0.f};
                au[mi][j] = (f32x4){0.f, 0.f, 0.f, 0.f};
            }
#pragma unroll 2
        for (int ks = 0; ks < 8; ++ks) {
            int k = ks * 32 + quad * 8;
            bf16x8 bvf[2], buf[2];
#pragma unroll
            for (int j = 0; j < 2; ++j) {
                int n = wave * 64 + (nc * 2 + j) * 16 + l15;
                bvf[j] = *(const bf16x8*)(Wvt + (size_t)n * 256 + k);
                buf[j] = *(const bf16x8*)(Wut + (size_t)n * 256 + k);
            }
            bf16x8 afr[4];
#pragma unroll
            for (int mi = 0; mi < 4; ++mi)
                afr[mi] = *(const bf16x8*)&Hs[(mi * 16 + l15) * 264 + k];
#pragma unroll
            for (int mi = 0; mi < 4; ++mi)
#pragma unroll
                for (int j = 0; j < 2; ++j) {
                    av[mi][j] = __builtin_amdgcn_mfma_f32_16x16x32_bf16(afr[mi], bvf[j], av[mi][j], 0, 0, 0);
                    au[mi][j] = __builtin_amdgcn_mfma_f32_16x16x32_bf16(afr[mi], buf[j], au[mi][j], 0, 0, 0);
                }
        }
        // epilogue: tanh * sigmoid * ww -> row partials
#pragma unroll
        for (int j = 0; j < 2; ++j) {
            int n = wave * 64 + (nc * 2 + j) * 16 + l15;
            float bvn = bv[n], bun = bu[n], wn = ww[n];
#pragma unroll
            for (int mi = 0; mi < 4; ++mi)
#pragma unroll
                for (int r = 0; r < 4; ++r) {
                    float tv = tanhf(av[mi][j][r] + bvn);
                    float su = 1.f / (1.f + expf(-(au[mi][j][r] + bun)));
                    rsum[mi][r] += tv * su * wn;
                }
        }
    }
    // reduce over the 16 lanes of each quad (cols), then across waves via LDS atomics
#pragma unroll
    for (int mi = 0; mi < 4; ++mi)
#pragma unroll
        for (int r = 0; r < 4; ++r) {
            float s = rsum[mi][r];
            s += __shfl_xor(s, 1);
            s += __shfl_xor(s, 2);
            s += __shfl_xor(s, 4);
            s += __shfl_xor(s, 8);
            if (l15 == 0) atomicAdd(&logits[mi * 16 + quad * 4 + r], s);
        }
    __syncthreads();   // all logit atomics done

    // finalize logits: + bw, mask
    if (tid < MT) {
        float lg = logits[tid] + bwv;
        if (mask[bag * TT + trow + tid]) lg = -INFINITY;
        logits[tid] = lg;
    }
    __syncthreads();

    // block-local softmax stats (wave 0)
    if (wave == 0) {
        float v = logits[lane];
        float mx = v;
#pragma unroll
        for (int off = 1; off < 64; off <<= 1) mx = fmaxf(mx, __shfl_xor(mx, off));
        float w = (mx == -INFINITY) ? 0.f : expf(v - mx);
        wrow[lane] = w;
        float l = w;
#pragma unroll
        for (int off = 1; off < 64; off <<= 1) l += __shfl_xor(l, off);
        if (lane == 0) { sc[0] = mx; sc[1] = l; }
    }
    __syncthreads();

    // weighted aggregation: acc[n] = sum_m w[m] * h[m][n]
    float a = 0.f;
#pragma unroll 8
    for (int m = 0; m < MT; ++m)
        a += wrow[m] * b2f(Hs[m * 264 + tid]);

    float* rec = P + (size_t)blk * PSTR;
    rec[2 + tid] = a;
    if (tid == 0) { rec[0] = sc[0]; rec[1] = sc[1]; }
}

// ---------------- final: per-bag reduction + classifier ----------------
__global__ void mil_final(const float* __restrict__ P,
                          const float* __restrict__ Wc,
                          const float* __restrict__ bc,
                          float* __restrict__ out) {
    const int bag = blockIdx.x;
    const int tid = threadIdx.x;
    __shared__ float marr[PBAG];
    __shared__ float earr[PBAG];
    __shared__ float red[4];
    __shared__ float wred[8];

    if (tid < PBAG) marr[tid] = P[(size_t)(bag * PBAG + tid) * PSTR + 0];
    __syncthreads();
    if (tid < PBAG) {   // waves 0,1 whole -> shuffles are wave-uniform
        float v = marr[tid];
#pragma unroll
        for (int off = 1; off < 64; off <<= 1) v = fmaxf(v, __shfl_xor(v, off));
        if ((tid & 63) == 0) red[tid >> 6] = v;
    }
    __syncthreads();
    const float M = fmaxf(red[0], red[1]);
    if (tid < PBAG) {
        float e = (marr[tid] == -INFINITY) ? 0.f : expf(marr[tid] - M);
        earr[tid] = e;
        float le = P[(size_t)(bag * PBAG + tid) * PSTR + 1] * e;
#pragma unroll
        for (int off = 1; off < 64; off <<= 1) le += __shfl_xor(le, off);
        if ((tid & 63) == 0) red[2 + (tid >> 6)] = le;
    }
    __syncthreads();
    const float L = red[2] + red[3];

    float accv = 0.f;
    for (int i = 0; i < PBAG; ++i)
        accv += earr[i] * P[(size_t)(bag * PBAG + i) * PSTR + 2 + tid];
    const float sr = accv / L;

    float p0 = sr * Wc[tid * 2 + 0];
    float p1 = sr * Wc[tid * 2 + 1];
#pragma unroll
    for (int off = 1; off < 64; off <<= 1) {
        p0 += __shfl_xor(p0, off);
        p1 += __shfl_xor(p1, off);
    }
    if ((tid & 63) == 0) {
        wred[(tid >> 6) * 2 + 0] = p0;
        wred[(tid >> 6) * 2 + 1] = p1;
    }
    __syncthreads();
    if (tid == 0) {
        out[bag * 2 + 0] = wred[0] + wred[2] + wred[4] + wred[6] + bc[0];
        out[bag * 2 + 1] = wred[1] + wred[3] + wred[5] + wred[7] + bc[1];
    }
}

extern "C" void kernel_launch(void* const* d_in, const int* in_sizes, int n_in,
                              void* d_out, int out_size, void* d_ws, size_t ws_size,
                              hipStream_t stream) {
    const float*         bags = (const float*)d_in[0];
    const unsigned char* mask = (const unsigned char*)d_in[1];
    const float*         W1   = (const float*)d_in[2];
    const float*         b1   = (const float*)d_in[3];
    const float*         Wv   = (const float*)d_in[4];
    const float*         bv   = (const float*)d_in[5];
    const float*         Wu   = (const float*)d_in[6];
    const float*         bu   = (const float*)d_in[7];
    const float*         ww   = (const float*)d_in[8];
    const float*         bw   = (const float*)d_in[9];
    const float*         Wc   = (const float*)d_in[10];
    const float*         bc   = (const float*)d_in[11];
    float* out = (float*)d_out;

    char* ws = (char*)d_ws;
    unsigned short* W1t = (unsigned short*)(ws);                    // 256*1024*2 = 524288 B
    unsigned short* Wvt = (unsigned short*)(ws + 524288);           // 131072 B
    unsigned short* Wut = (unsigned short*)(ws + 655360);           // 131072 B
    float*          P   = (float*)(ws + 786432);                    // 1024*260*4 B

    mil_prep<<<96, 256, 0, stream>>>(W1, Wv, Wu, W1t, Wvt, Wut);
    mil_main<<<NBLK, 256, 0, stream>>>(bags, mask, b1, bv, bu, ww, bw, W1t, Wvt, Wut, P);
    mil_final<<<BB, 256, 0, stream>>>(P, Wc, bc, out);
}